// Round 11
// baseline (173.437 us; speedup 1.0000x reference)
//
#include <hip/hip_runtime.h>

// RelGraphConv basis-decomposition forward, MI355X.
//
// Input-space reformulation:
//   g[d, b, :] = sum_{e: dst_e = d} w_comp[et_e, b] * feat[src_e, :]   (b = 0,1)
//   out[d]     = g[d,0] @ V0 + g[d,1] @ V1 + feat[d] @ W_loop + bias
//
// Pipeline:
//   k_cvt (feat -> bf16) ; memset bcnt -> k_bhist -> k_bscan -> k_bscatter
//   (coarse 391-bucket multisplit) -> k_fine (per-bucket exact per-node CSR)
//   -> k_gather_post (FUSED gather + dense [g0,g1,feat](192)->64 GEMM).
//
// r11 gather: wave w owns CONTIGUOUS node pair (grp*8+2w, +2w+1) -> one
// contiguous CSR run per wave (full 8-batches, single prologue); uniform
// branch on the node boundary selects accumulator set; next-batch entries
// prefetched under the current batch's feat-load latency.

constexpr int N_NODES  = 100000;
constexpr int N_EDGES  = 1600000;
constexpr int IN_FEAT  = 64;
constexpr int OUT_FEAT = 64;

constexpr int BN = 256;                                // nodes per bucket
constexpr int NB = (N_NODES + BN - 1) / BN;            // 391 buckets
constexpr int SC_CHUNK = 4096;                         // edges per scatter block

constexpr int NODES_PER_GRP = 8;
constexpr int N_GRP  = N_NODES / NODES_PER_GRP;        // 12500 (exact)
constexpr int GP_GRID = 2500;                          // 5 groups per block, exact

// entry pack: dst_low(8) | src(17) | etype(6)
__device__ __forceinline__ unsigned pack_entry(int d, int s, int r) {
    return (unsigned)(d & (BN - 1)) | ((unsigned)s << 8) | ((unsigned)r << 25);
}

__device__ __forceinline__ unsigned bf16_rne(float f) {
    unsigned b = __float_as_uint(f);
    b += 0x7fffu + ((b >> 16) & 1u);
    return b >> 16;
}

// ---------------------------------------------------------------- f32->bf16
__global__ __launch_bounds__(256) void k_cvt(const float* __restrict__ feat,
                                             unsigned* __restrict__ fbf) {
    const int total = N_NODES * 16;    // float4 count
    const float4* __restrict__ f4 = (const float4*)feat;
    uint2* __restrict__ o2 = (uint2*)fbf;
    for (int i = blockIdx.x * 256 + threadIdx.x; i < total; i += gridDim.x * 256) {
        const float4 f = f4[i];
        uint2 o;
        o.x = bf16_rne(f.x) | (bf16_rne(f.y) << 16);
        o.y = bf16_rne(f.z) | (bf16_rne(f.w) << 16);
        o2[i] = o;
    }
}

// ---------------------------------------------------------------- coarse hist
__global__ __launch_bounds__(256) void k_bhist(const int* __restrict__ dst,
                                               int* __restrict__ bcnt) {
    __shared__ int hist[NB];
    const int t = threadIdx.x;
    for (int i = t; i < NB; i += 256) hist[i] = 0;
    __syncthreads();
    const int cbase = blockIdx.x * 2048;
    #pragma unroll
    for (int k = 0; k < 8; ++k) {
        const int e = cbase + k * 256 + t;
        if (e < N_EDGES) atomicAdd(&hist[dst[e] >> 8], 1);
    }
    __syncthreads();
    for (int i = t; i < NB; i += 256)
        if (hist[i]) atomicAdd(&bcnt[i], hist[i]);
}

// ---------------------------------------------------------------- coarse scan
__global__ __launch_bounds__(512) void k_bscan(const int* __restrict__ bcnt,
                                               int* __restrict__ bbase,
                                               int* __restrict__ bcursor) {
    __shared__ int part[512];
    const int t = threadIdx.x;
    const int v = (t < NB) ? bcnt[t] : 0;
    part[t] = v;
    __syncthreads();
    for (int d = 1; d < 512; d <<= 1) {
        const int u = (t >= d) ? part[t - d] : 0;
        __syncthreads();
        part[t] += u;
        __syncthreads();
    }
    if (t < NB) {
        const int ex = part[t] - v;   // exclusive
        bbase[t] = ex;
        bcursor[t] = ex;
    }
    if (t == 0) bbase[NB] = N_EDGES;
}

// ---------------------------------------------------------------- multisplit
__global__ __launch_bounds__(256) void k_bscatter(const int* __restrict__ src,
                                                  const int* __restrict__ dst,
                                                  const int* __restrict__ et,
                                                  int* __restrict__ bcursor,
                                                  unsigned* __restrict__ sorted_c) {
    __shared__ int hist[NB], gb[NB], lcur[NB];
    const int t = threadIdx.x;
    const int cbase = blockIdx.x * SC_CHUNK;
    for (int i = t; i < NB; i += 256) { hist[i] = 0; lcur[i] = 0; }
    __syncthreads();
    #pragma unroll 1
    for (int k = 0; k < SC_CHUNK / 256; ++k) {
        const int e = cbase + k * 256 + t;
        if (e < N_EDGES) atomicAdd(&hist[dst[e] >> 8], 1);
    }
    __syncthreads();
    for (int i = t; i < NB; i += 256) {
        const int c = hist[i];
        gb[i] = c ? atomicAdd(&bcursor[i], c) : 0;
    }
    __syncthreads();
    #pragma unroll 1
    for (int k = 0; k < SC_CHUNK / 256; ++k) {
        const int e = cbase + k * 256 + t;
        if (e < N_EDGES) {
            const int d = dst[e];
            const int bkt = d >> 8;
            const int r = atomicAdd(&lcur[bkt], 1);
            sorted_c[gb[bkt] + r] = pack_entry(d, src[e], et[e]);
        }
    }
}

// ---------------------------------------------------------------- fine CSR
__global__ __launch_bounds__(256) void k_fine(const unsigned* __restrict__ sorted_c,
                                              const int* __restrict__ bbase,
                                              int* __restrict__ offsets,
                                              unsigned* __restrict__ sorted_f) {
    __shared__ int cnt[BN];
    __shared__ int part[BN];
    __shared__ int cur[BN];
    const int t = threadIdx.x;
    const int b = blockIdx.x;
    cnt[t] = 0;
    __syncthreads();
    const int base = bbase[b];
    const int end  = bbase[b + 1];
    for (int k = base + t; k < end; k += 256)
        atomicAdd(&cnt[sorted_c[k] & (BN - 1)], 1);
    __syncthreads();
    const int v = cnt[t];
    part[t] = v;
    __syncthreads();
    for (int d = 1; d < BN; d <<= 1) {
        const int u = (t >= d) ? part[t - d] : 0;
        __syncthreads();
        part[t] += u;
        __syncthreads();
    }
    const int node = b * BN + t;
    const int off = base + part[t] - v;   // exclusive within bucket
    if (node < N_NODES) offsets[node] = off;
    cur[t] = off;
    if (b == NB - 1 && t == 0) offsets[N_NODES] = N_EDGES;
    __syncthreads();
    for (int k = base + t; k < end; k += 256) {
        const unsigned en = sorted_c[k];
        const int pos = atomicAdd(&cur[en & (BN - 1)], 1);
        sorted_f[pos] = en;
    }
}

// ---------------------------------------------------------------- fused
// 256 threads = 4 waves; 2500 blocks x exactly 5 groups of 8 nodes.
// Phase 1: wave w streams the contiguous CSR run of nodes (2w, 2w+1):
//   8-deep batches, next-batch entry prefetch, uniform-branch accumulator
//   select at the node boundary m. Results -> LDS slots 2w, 2w+1.
// Phase 2: thread (seg=w, col=lane) does the 48-row K-segment of the
//   192->64 GEMM for all 8 nodes; LDS partial reduce; coalesced out.
__global__ __launch_bounds__(256, 4) void k_gather_post(
    const int*      __restrict__ offsets,
    const unsigned* __restrict__ sorted_f,
    const float*    __restrict__ w_comp,      // (64, 2)
    const float*    __restrict__ feat,        // (N, 64) f32 (self-loop row)
    const unsigned short* __restrict__ fbs,   // (N, 64) bf16
    const float*    __restrict__ weight,      // (2, 64, 64)
    const float*    __restrict__ loop_weight, // (64, 64)
    const float*    __restrict__ h_bias,      // (64,)
    float*          __restrict__ out)         // (N, 64)
{
    __shared__ float4 Lin4[NODES_PER_GRP][48];  // [node][192 f32]: g0|g1|feat
    __shared__ float  ps[4][NODES_PER_GRP][64]; // [seg][node][col]
    float* Lin = (float*)Lin4;

    const int tid  = threadIdx.x;
    const int lane = tid & 63;                // = col in phase 2
    const int w    = tid >> 6;                // wave = K-seg in phase 2

    // Wcat (= [V0; V1; W_loop]) column segment, rows w*48..w*48+47.
    float wcol[48];
    #pragma unroll
    for (int i = 0; i < 48; ++i) {
        const int r = w * 48 + i;
        wcol[i] = (r < 64)  ? weight[r * 64 + lane]
                : (r < 128) ? weight[64 * 64 + (r - 64) * 64 + lane]
                            : loop_weight[(r - 128) * 64 + lane];
    }
    const float bias = h_bias[lane];
    const float2* __restrict__ wc = (const float2*)w_comp;

    #pragma unroll 1
    for (int g = 0; g < N_GRP / GP_GRID; ++g) {
        const int grp = blockIdx.x + g * GP_GRID;

        __syncthreads();   // prior iteration's ps reads complete; Lin free

        // ---- Phase 1: one contiguous stream covering nodes 2w, 2w+1 ----
        const int nA = __builtin_amdgcn_readfirstlane(grp * 8 + 2 * w);
        const int s  = __builtin_amdgcn_readfirstlane(offsets[nA]);
        const int m  = __builtin_amdgcn_readfirstlane(offsets[nA + 1]);
        const int e  = __builtin_amdgcn_readfirstlane(offsets[nA + 2]);
        const float fvA = feat[(size_t)nA * 64 + lane];
        const float fvB = feat[(size_t)(nA + 1) * 64 + lane];

        float aA0 = 0.f, aA1 = 0.f, bA0 = 0.f, bA1 = 0.f;   // node 2w
        float aB0 = 0.f, aB1 = 0.f, bB0 = 0.f, bB1 = 0.f;   // node 2w+1
        int k = s;
        unsigned p[8];
        if (k + 7 < e) {
            #pragma unroll
            for (int i = 0; i < 8; ++i) p[i] = sorted_f[k + i];   // uniform -> s_load
        }
        #pragma unroll 1
        for (; k + 7 < e; ) {
            float f[8];
            #pragma unroll
            for (int i = 0; i < 8; ++i)
                f[i] = __uint_as_float(
                    (unsigned)fbs[(size_t)((p[i] >> 8) & 0x1FFFF) * 64 + lane] << 16);
            unsigned pn[8];
            const bool more = (k + 15 < e);
            if (more) {
                #pragma unroll
                for (int i = 0; i < 8; ++i) pn[i] = sorted_f[k + 8 + i];  // prefetch
            }
            #pragma unroll
            for (int i = 0; i < 8; ++i) {
                const float2 c = wc[p[i] >> 25];
                if (k + i < m) {   // wave-uniform branch
                    if (i & 1) { aA1 = fmaf(c.x, f[i], aA1); bA1 = fmaf(c.y, f[i], bA1); }
                    else       { aA0 = fmaf(c.x, f[i], aA0); bA0 = fmaf(c.y, f[i], bA0); }
                } else {
                    if (i & 1) { aB1 = fmaf(c.x, f[i], aB1); bB1 = fmaf(c.y, f[i], bB1); }
                    else       { aB0 = fmaf(c.x, f[i], aB0); bB0 = fmaf(c.y, f[i], bB0); }
                }
            }
            k += 8;
            if (more) {
                #pragma unroll
                for (int i = 0; i < 8; ++i) p[i] = pn[i];
            }
        }
        for (; k + 3 < e; k += 4) {
            unsigned p4[4]; float f4v[4];
            #pragma unroll
            for (int i = 0; i < 4; ++i) p4[i] = sorted_f[k + i];
            #pragma unroll
            for (int i = 0; i < 4; ++i)
                f4v[i] = __uint_as_float(
                    (unsigned)fbs[(size_t)((p4[i] >> 8) & 0x1FFFF) * 64 + lane] << 16);
            #pragma unroll
            for (int i = 0; i < 4; ++i) {
                const float2 c = wc[p4[i] >> 25];
                if (k + i < m) {
                    if (i & 1) { aA1 = fmaf(c.x, f4v[i], aA1); bA1 = fmaf(c.y, f4v[i], bA1); }
                    else       { aA0 = fmaf(c.x, f4v[i], aA0); bA0 = fmaf(c.y, f4v[i], bA0); }
                } else {
                    if (i & 1) { aB1 = fmaf(c.x, f4v[i], aB1); bB1 = fmaf(c.y, f4v[i], bB1); }
                    else       { aB0 = fmaf(c.x, f4v[i], aB0); bB0 = fmaf(c.y, f4v[i], bB0); }
                }
            }
        }
        for (; k < e; ++k) {
            const unsigned p0 = sorted_f[k];
            const float f0 = __uint_as_float(
                (unsigned)fbs[(size_t)((p0 >> 8) & 0x1FFFF) * 64 + lane] << 16);
            const float2 c0 = wc[p0 >> 25];
            if (k < m) { aA0 = fmaf(c0.x, f0, aA0); bA0 = fmaf(c0.y, f0, bA0); }
            else       { aB0 = fmaf(c0.x, f0, aB0); bB0 = fmaf(c0.y, f0, bB0); }
        }

        const int slotA = 2 * w, slotB = 2 * w + 1;
        Lin[slotA * 192 + lane]       = aA0 + aA1;
        Lin[slotA * 192 + 64 + lane]  = bA0 + bA1;
        Lin[slotA * 192 + 128 + lane] = fvA;
        Lin[slotB * 192 + lane]       = aB0 + aB1;
        Lin[slotB * 192 + 64 + lane]  = bB0 + bB1;
        Lin[slotB * 192 + 128 + lane] = fvB;
        __syncthreads();

        // ---- Phase 2: K-segment GEMM over 8 nodes ----
        #pragma unroll
        for (int j = 0; j < NODES_PER_GRP; ++j) {
            const float4* v4 = (const float4*)&Lin4[0][0] + j * 48 + w * 12;
            float p0 = 0.f, p1 = 0.f;
            #pragma unroll
            for (int i4 = 0; i4 < 12; i4 += 2) {
                const float4 x = v4[i4];       // uniform -> LDS broadcast
                const float4 y = v4[i4 + 1];
                p0 = fmaf(x.x, wcol[4 * i4 + 0], p0);
                p0 = fmaf(x.y, wcol[4 * i4 + 1], p0);
                p0 = fmaf(x.z, wcol[4 * i4 + 2], p0);
                p0 = fmaf(x.w, wcol[4 * i4 + 3], p0);
                p1 = fmaf(y.x, wcol[4 * i4 + 4], p1);
                p1 = fmaf(y.y, wcol[4 * i4 + 5], p1);
                p1 = fmaf(y.z, wcol[4 * i4 + 6], p1);
                p1 = fmaf(y.w, wcol[4 * i4 + 7], p1);
            }
            ps[w][j][lane] = p0 + p1;
        }
        __syncthreads();

        // Two outputs per thread: node slots 2w, 2w+1. Coalesced per wave.
        #pragma unroll
        for (int half = 0; half < 2; ++half) {
            const int slot = 2 * w + half;
            out[(size_t)(grp * 8 + slot) * 64 + lane] =
                ps[0][slot][lane] + ps[1][slot][lane] +
                ps[2][slot][lane] + ps[3][slot][lane] + bias;
        }
    }
}

// ---------------------------------------------------------------- launch
extern "C" void kernel_launch(void* const* d_in, const int* in_sizes, int n_in,
                              void* d_out, int out_size, void* d_ws, size_t ws_size,
                              hipStream_t stream) {
    const float* feat        = (const float*)d_in[0];
    const float* weight      = (const float*)d_in[1];
    const float* w_comp      = (const float*)d_in[2];
    const float* loop_weight = (const float*)d_in[3];
    const float* h_bias      = (const float*)d_in[4];
    const int*   src         = (const int*)d_in[5];
    const int*   dst         = (const int*)d_in[6];
    const int*   etypes      = (const int*)d_in[7];
    float* out = (float*)d_out;

    // ws layout (4B units), ~26 MB total, no aliasing:
    unsigned* sorted_c = (unsigned*)d_ws;                     // 1.6M u32
    unsigned* sorted_f = sorted_c + N_EDGES;                  // 1.6M u32
    unsigned* fbf      = sorted_f + N_EDGES;                  // 3.2M u32 (bf16 feat)
    int*      offsets  = (int*)(fbf + N_NODES * 32);          // N+1
    int*      bcnt     = offsets + (N_NODES + 1);             // NB
    int*      bbase    = bcnt + NB;                           // NB+1
    int*      bcursor  = bbase + NB + 1;                      // NB

    k_cvt<<<2048, 256, 0, stream>>>(feat, fbf);
    hipMemsetAsync(bcnt, 0, NB * sizeof(int), stream);
    k_bhist<<<(N_EDGES + 2047) / 2048, 256, 0, stream>>>(dst, bcnt);
    k_bscan<<<1, 512, 0, stream>>>(bcnt, bbase, bcursor);
    k_bscatter<<<(N_EDGES + SC_CHUNK - 1) / SC_CHUNK, 256, 0, stream>>>(
        src, dst, etypes, bcursor, sorted_c);
    k_fine<<<NB, BN, 0, stream>>>(sorted_c, bbase, offsets, sorted_f);
    k_gather_post<<<GP_GRID, 256, 0, stream>>>(offsets, sorted_f, w_comp, feat,
                                               (const unsigned short*)fbf,
                                               weight, loop_weight, h_bias, out);
}

// Round 12
// 168.411 us; speedup vs baseline: 1.0298x; 1.0298x over previous
//
#include <hip/hip_runtime.h>

// RelGraphConv basis-decomposition forward, MI355X.
//
// Input-space reformulation:
//   g[d, b, :] = sum_{e: dst_e = d} w_comp[et_e, b] * feat[src_e, :]   (b = 0,1)
//   out[d]     = g[d,0] @ V0 + g[d,1] @ V1 + feat[d] @ W_loop + bias
//
// Pipeline:
//   k_cvt (feat -> bf16) ; memset bcnt -> k_bhist -> k_bscan -> k_bscatter
//   (coarse 391-bucket multisplit) -> k_fine (per-bucket exact per-node CSR)
//   -> k_gather_post (FUSED gather + dense [g0,g1,feat](192)->64 GEMM).
//
// r12: 512-thread blocks (8 waves), ONE group of 8 nodes per block, grid
// 12500. Each wave owns one node with the r10-proven gather loop (8-deep
// batches). Phase 2: 8 K-segments of 24 rows. Rationale: r10/r11 showed
// phase 1 is stall-bound at ~15 waves/CU; finer blocks + 8 waves/block
// raise co-resident waves (VGPR 44 and LDS 22.5KB both permit 32/CU).

constexpr int N_NODES  = 100000;
constexpr int N_EDGES  = 1600000;
constexpr int IN_FEAT  = 64;
constexpr int OUT_FEAT = 64;

constexpr int BN = 256;                                // nodes per bucket
constexpr int NB = (N_NODES + BN - 1) / BN;            // 391 buckets
constexpr int SC_CHUNK = 4096;                         // edges per scatter block

constexpr int NODES_PER_GRP = 8;
constexpr int N_GRP  = N_NODES / NODES_PER_GRP;        // 12500 (exact)

// entry pack: dst_low(8) | src(17) | etype(6)
__device__ __forceinline__ unsigned pack_entry(int d, int s, int r) {
    return (unsigned)(d & (BN - 1)) | ((unsigned)s << 8) | ((unsigned)r << 25);
}

__device__ __forceinline__ unsigned bf16_rne(float f) {
    unsigned b = __float_as_uint(f);
    b += 0x7fffu + ((b >> 16) & 1u);
    return b >> 16;
}

// ---------------------------------------------------------------- f32->bf16
__global__ __launch_bounds__(256) void k_cvt(const float* __restrict__ feat,
                                             unsigned* __restrict__ fbf) {
    const int total = N_NODES * 16;    // float4 count
    const float4* __restrict__ f4 = (const float4*)feat;
    uint2* __restrict__ o2 = (uint2*)fbf;
    for (int i = blockIdx.x * 256 + threadIdx.x; i < total; i += gridDim.x * 256) {
        const float4 f = f4[i];
        uint2 o;
        o.x = bf16_rne(f.x) | (bf16_rne(f.y) << 16);
        o.y = bf16_rne(f.z) | (bf16_rne(f.w) << 16);
        o2[i] = o;
    }
}

// ---------------------------------------------------------------- coarse hist
__global__ __launch_bounds__(256) void k_bhist(const int* __restrict__ dst,
                                               int* __restrict__ bcnt) {
    __shared__ int hist[NB];
    const int t = threadIdx.x;
    for (int i = t; i < NB; i += 256) hist[i] = 0;
    __syncthreads();
    const int cbase = blockIdx.x * 2048;
    #pragma unroll
    for (int k = 0; k < 8; ++k) {
        const int e = cbase + k * 256 + t;
        if (e < N_EDGES) atomicAdd(&hist[dst[e] >> 8], 1);
    }
    __syncthreads();
    for (int i = t; i < NB; i += 256)
        if (hist[i]) atomicAdd(&bcnt[i], hist[i]);
}

// ---------------------------------------------------------------- coarse scan
__global__ __launch_bounds__(512) void k_bscan(const int* __restrict__ bcnt,
                                               int* __restrict__ bbase,
                                               int* __restrict__ bcursor) {
    __shared__ int part[512];
    const int t = threadIdx.x;
    const int v = (t < NB) ? bcnt[t] : 0;
    part[t] = v;
    __syncthreads();
    for (int d = 1; d < 512; d <<= 1) {
        const int u = (t >= d) ? part[t - d] : 0;
        __syncthreads();
        part[t] += u;
        __syncthreads();
    }
    if (t < NB) {
        const int ex = part[t] - v;   // exclusive
        bbase[t] = ex;
        bcursor[t] = ex;
    }
    if (t == 0) bbase[NB] = N_EDGES;
}

// ---------------------------------------------------------------- multisplit
__global__ __launch_bounds__(256) void k_bscatter(const int* __restrict__ src,
                                                  const int* __restrict__ dst,
                                                  const int* __restrict__ et,
                                                  int* __restrict__ bcursor,
                                                  unsigned* __restrict__ sorted_c) {
    __shared__ int hist[NB], gb[NB], lcur[NB];
    const int t = threadIdx.x;
    const int cbase = blockIdx.x * SC_CHUNK;
    for (int i = t; i < NB; i += 256) { hist[i] = 0; lcur[i] = 0; }
    __syncthreads();
    #pragma unroll 1
    for (int k = 0; k < SC_CHUNK / 256; ++k) {
        const int e = cbase + k * 256 + t;
        if (e < N_EDGES) atomicAdd(&hist[dst[e] >> 8], 1);
    }
    __syncthreads();
    for (int i = t; i < NB; i += 256) {
        const int c = hist[i];
        gb[i] = c ? atomicAdd(&bcursor[i], c) : 0;
    }
    __syncthreads();
    #pragma unroll 1
    for (int k = 0; k < SC_CHUNK / 256; ++k) {
        const int e = cbase + k * 256 + t;
        if (e < N_EDGES) {
            const int d = dst[e];
            const int bkt = d >> 8;
            const int r = atomicAdd(&lcur[bkt], 1);
            sorted_c[gb[bkt] + r] = pack_entry(d, src[e], et[e]);
        }
    }
}

// ---------------------------------------------------------------- fine CSR
__global__ __launch_bounds__(256) void k_fine(const unsigned* __restrict__ sorted_c,
                                              const int* __restrict__ bbase,
                                              int* __restrict__ offsets,
                                              unsigned* __restrict__ sorted_f) {
    __shared__ int cnt[BN];
    __shared__ int part[BN];
    __shared__ int cur[BN];
    const int t = threadIdx.x;
    const int b = blockIdx.x;
    cnt[t] = 0;
    __syncthreads();
    const int base = bbase[b];
    const int end  = bbase[b + 1];
    for (int k = base + t; k < end; k += 256)
        atomicAdd(&cnt[sorted_c[k] & (BN - 1)], 1);
    __syncthreads();
    const int v = cnt[t];
    part[t] = v;
    __syncthreads();
    for (int d = 1; d < BN; d <<= 1) {
        const int u = (t >= d) ? part[t - d] : 0;
        __syncthreads();
        part[t] += u;
        __syncthreads();
    }
    const int node = b * BN + t;
    const int off = base + part[t] - v;   // exclusive within bucket
    if (node < N_NODES) offsets[node] = off;
    cur[t] = off;
    if (b == NB - 1 && t == 0) offsets[N_NODES] = N_EDGES;
    __syncthreads();
    for (int k = base + t; k < end; k += 256) {
        const unsigned en = sorted_c[k];
        const int pos = atomicAdd(&cur[en & (BN - 1)], 1);
        sorted_f[pos] = en;
    }
}

// ---------------------------------------------------------------- fused
// 512 threads = 8 waves; 12500 blocks, one group of 8 nodes each.
// Phase 1: wave w register-gathers node grp*8+w (8-deep unroll -> 8 bf16
//          row loads in flight, 128 B/edge) -> LDS slot w.
// Phase 2: thread (seg=w, col=lane) does the 24-row K-segment of the
//          192->64 GEMM for all 8 nodes; LDS partial reduce; coalesced out.
__global__ __launch_bounds__(512, 4) void k_gather_post(
    const int*      __restrict__ offsets,
    const unsigned* __restrict__ sorted_f,
    const float*    __restrict__ w_comp,      // (64, 2)
    const float*    __restrict__ feat,        // (N, 64) f32 (self-loop row)
    const unsigned short* __restrict__ fbs,   // (N, 64) bf16
    const float*    __restrict__ weight,      // (2, 64, 64) = Wcat rows 0..127
    const float*    __restrict__ loop_weight, // (64, 64)    = Wcat rows 128..191
    const float*    __restrict__ h_bias,      // (64,)
    float*          __restrict__ out)         // (N, 64)
{
    __shared__ float4 Lin4[NODES_PER_GRP][48];  // [node][192 f32]: g0|g1|feat
    __shared__ float  ps[8][NODES_PER_GRP][64]; // [seg][node][col]
    float* Lin = (float*)Lin4;

    const int tid  = threadIdx.x;
    const int lane = tid & 63;                // = col in phase 2
    const int w    = tid >> 6;                // wave = node slot = K-seg

    // Wcat (= [V0; V1; W_loop]) column segment, rows w*24..w*24+23.
    // Rows < 128 are contiguous in weight (b*4096 + i*64 + o = r*64 + o).
    float wcol[24];
    #pragma unroll
    for (int i = 0; i < 24; ++i) {
        const int r = w * 24 + i;
        wcol[i] = (r < 128) ? weight[r * 64 + lane]
                            : loop_weight[(r - 128) * 64 + lane];
    }
    const float bias = h_bias[lane];
    const float2* __restrict__ wc = (const float2*)w_comp;

    const int grp = blockIdx.x;

    // ---- Phase 1: each wave gathers its node ----
    {
        const int n = __builtin_amdgcn_readfirstlane(grp * 8 + w);
        const int start = __builtin_amdgcn_readfirstlane(offsets[n]);
        const int end   = __builtin_amdgcn_readfirstlane(offsets[n + 1]);
        const float fv = feat[(size_t)n * 64 + lane];

        float a0 = 0.f, b0 = 0.f, a1 = 0.f, b1 = 0.f;
        int k = start;
        for (; k + 7 < end; k += 8) {
            unsigned p[8]; float f[8];
            #pragma unroll
            for (int i = 0; i < 8; ++i) p[i] = sorted_f[k + i];   // uniform -> s_load
            #pragma unroll
            for (int i = 0; i < 8; ++i)
                f[i] = __uint_as_float(
                    (unsigned)fbs[(size_t)((p[i] >> 8) & 0x1FFFF) * 64 + lane] << 16);
            #pragma unroll
            for (int i = 0; i < 8; ++i) {
                const float2 c = wc[p[i] >> 25];
                if (i & 1) { a1 = fmaf(c.x, f[i], a1); b1 = fmaf(c.y, f[i], b1); }
                else       { a0 = fmaf(c.x, f[i], a0); b0 = fmaf(c.y, f[i], b0); }
            }
        }
        for (; k + 3 < end; k += 4) {
            unsigned p[4]; float f[4];
            #pragma unroll
            for (int i = 0; i < 4; ++i) p[i] = sorted_f[k + i];
            #pragma unroll
            for (int i = 0; i < 4; ++i)
                f[i] = __uint_as_float(
                    (unsigned)fbs[(size_t)((p[i] >> 8) & 0x1FFFF) * 64 + lane] << 16);
            #pragma unroll
            for (int i = 0; i < 4; ++i) {
                const float2 c = wc[p[i] >> 25];
                if (i & 1) { a1 = fmaf(c.x, f[i], a1); b1 = fmaf(c.y, f[i], b1); }
                else       { a0 = fmaf(c.x, f[i], a0); b0 = fmaf(c.y, f[i], b0); }
            }
        }
        for (; k < end; ++k) {
            const unsigned p0 = sorted_f[k];
            const float f0 = __uint_as_float(
                (unsigned)fbs[(size_t)((p0 >> 8) & 0x1FFFF) * 64 + lane] << 16);
            const float2 c0 = wc[p0 >> 25];
            a0 = fmaf(c0.x, f0, a0); b0 = fmaf(c0.y, f0, b0);
        }
        Lin[w * 192 + lane]       = a0 + a1;
        Lin[w * 192 + 64 + lane]  = b0 + b1;
        Lin[w * 192 + 128 + lane] = fv;
    }
    __syncthreads();

    // ---- Phase 2: 24-row K-segment GEMM over 8 nodes ----
    #pragma unroll
    for (int j = 0; j < NODES_PER_GRP; ++j) {
        const float4* v4 = &Lin4[j][w * 6];
        float p0 = 0.f, p1 = 0.f;
        #pragma unroll
        for (int i4 = 0; i4 < 6; i4 += 2) {
            const float4 x = v4[i4];       // uniform -> LDS broadcast
            const float4 y = v4[i4 + 1];
            p0 = fmaf(x.x, wcol[4 * i4 + 0], p0);
            p0 = fmaf(x.y, wcol[4 * i4 + 1], p0);
            p0 = fmaf(x.z, wcol[4 * i4 + 2], p0);
            p0 = fmaf(x.w, wcol[4 * i4 + 3], p0);
            p1 = fmaf(y.x, wcol[4 * i4 + 4], p1);
            p1 = fmaf(y.y, wcol[4 * i4 + 5], p1);
            p1 = fmaf(y.z, wcol[4 * i4 + 6], p1);
            p1 = fmaf(y.w, wcol[4 * i4 + 7], p1);
        }
        ps[w][j][lane] = p0 + p1;
    }
    __syncthreads();

    // One output per thread: node slot = w, col = lane. Coalesced.
    float acc = bias;
    #pragma unroll
    for (int seg = 0; seg < 8; ++seg) acc += ps[seg][w][lane];
    out[(size_t)(grp * 8 + w) * 64 + lane] = acc;
}

// ---------------------------------------------------------------- launch
extern "C" void kernel_launch(void* const* d_in, const int* in_sizes, int n_in,
                              void* d_out, int out_size, void* d_ws, size_t ws_size,
                              hipStream_t stream) {
    const float* feat        = (const float*)d_in[0];
    const float* weight      = (const float*)d_in[1];
    const float* w_comp      = (const float*)d_in[2];
    const float* loop_weight = (const float*)d_in[3];
    const float* h_bias      = (const float*)d_in[4];
    const int*   src         = (const int*)d_in[5];
    const int*   dst         = (const int*)d_in[6];
    const int*   etypes      = (const int*)d_in[7];
    float* out = (float*)d_out;

    // ws layout (4B units), ~26 MB total, no aliasing:
    unsigned* sorted_c = (unsigned*)d_ws;                     // 1.6M u32
    unsigned* sorted_f = sorted_c + N_EDGES;                  // 1.6M u32
    unsigned* fbf      = sorted_f + N_EDGES;                  // 3.2M u32 (bf16 feat)
    int*      offsets  = (int*)(fbf + N_NODES * 32);          // N+1
    int*      bcnt     = offsets + (N_NODES + 1);             // NB
    int*      bbase    = bcnt + NB;                           // NB+1
    int*      bcursor  = bbase + NB + 1;                      // NB

    k_cvt<<<2048, 256, 0, stream>>>(feat, fbf);
    hipMemsetAsync(bcnt, 0, NB * sizeof(int), stream);
    k_bhist<<<(N_EDGES + 2047) / 2048, 256, 0, stream>>>(dst, bcnt);
    k_bscan<<<1, 512, 0, stream>>>(bcnt, bbase, bcursor);
    k_bscatter<<<(N_EDGES + SC_CHUNK - 1) / SC_CHUNK, 256, 0, stream>>>(
        src, dst, etypes, bcursor, sorted_c);
    k_fine<<<NB, BN, 0, stream>>>(sorted_c, bbase, offsets, sorted_f);
    k_gather_post<<<N_GRP, 512, 0, stream>>>(offsets, sorted_f, w_comp, feat,
                                             (const unsigned short*)fbf,
                                             weight, loop_weight, h_bias, out);
}